// Round 10
// baseline (91.421 us; speedup 1.0000x reference)
//
#include <hip/hip_runtime.h>
#include <stdint.h>

typedef unsigned short u16;
typedef __attribute__((ext_vector_type(8))) short short8;
typedef __attribute__((ext_vector_type(4))) float f32x4;

#define BATCH 4
#define SEQ   2048
#define DIN   768
#define DK    128
#define DV    768
#define MTOT  (BATCH*SEQ)   // 8192
#define NQKV  1024          // 128 q + 128 k + 768 v

__device__ __forceinline__ u16 f2bf(float f) {
  union { float f; uint32_t u; } v; v.f = f;
  uint32_t r = v.u + 0x7FFFu + ((v.u >> 16) & 1u);
  return (u16)(r >> 16);
}

template<int N> __device__ __forceinline__ void wait_vmcnt() {
  if constexpr (N == 0) asm volatile("s_waitcnt vmcnt(0)" ::: "memory");
  else if constexpr (N == 5) asm volatile("s_waitcnt vmcnt(5)" ::: "memory");
}

#define GLOAD_LDS(SRC, DST) \
  __builtin_amdgcn_global_load_lds( \
      (const __attribute__((address_space(1))) unsigned int*)(SRC), \
      (__attribute__((address_space(3))) unsigned int*)(DST), 16, 0, 0)

// ---------------- K0: prep = convert_x + pack weights/bias ----------------
__global__ __launch_bounds__(256) void prep(
    const float* __restrict__ x, u16* __restrict__ xb,
    const float* __restrict__ Wq, const float* __restrict__ bq,
    const float* __restrict__ Wk, const float* __restrict__ bk,
    const float* __restrict__ Wv, const float* __restrict__ bv,
    u16* __restrict__ WbT, float* __restrict__ biasP) {
  const float qs = 0.088388347648318447f;  // 1/sqrt(128)
  __shared__ u16 tile[64][72];
  int b = blockIdx.x;
  int tid = threadIdx.x;
  if (b < 6144) {               // convert x -> bf16
    int i = (b * 256 + tid) * 4;
    float4 v = *(const float4*)(x + i);
    u16 o[4] = { f2bf(v.x), f2bf(v.y), f2bf(v.z), f2bf(v.w) };
    *(uint2*)(xb + i) = *(const uint2*)o;
    return;
  }
  int bid2 = b - 6144;          // 0..191 : pack weights (12 x 16)
  int y   = bid2 / 12;
  int i0  = (bid2 - y * 12) * 64;
  const float* W; u16* dst; int ldw, nb; float sc;
  if (y < 2)      { W = Wq; dst = WbT;                      ldw = DK; sc = qs;   nb = y;     }
  else if (y < 4) { W = Wk; dst = WbT + (size_t)DK * DIN;   ldw = DK; sc = 1.0f; nb = y - 2; }
  else            { W = Wv; dst = WbT + (size_t)2*DK * DIN; ldw = DV; sc = 1.0f; nb = y - 4; }
  int n0 = nb * 64;
  if (i0 == 0 && y == 0) {
    for (int n = tid; n < NQKV; n += 256)
      biasP[n] = (n < DK) ? bq[n] * qs : (n < 2*DK ? bk[n - DK] : bv[n - 2*DK]);
  }
  int tr = tid >> 2;
  int tc = (tid & 3) * 16;
  const float* src = W + (size_t)(i0 + tr) * ldw + n0 + tc;
  u16 o[16];
#pragma unroll
  for (int u = 0; u < 16; u += 4) {
    float4 v = *(const float4*)(src + u);
    o[u] = f2bf(v.x * sc); o[u+1] = f2bf(v.y * sc); o[u+2] = f2bf(v.z * sc); o[u+3] = f2bf(v.w * sc);
  }
  *(uint4*)&tile[tr][tc]     = *(const uint4*)&o[0];
  *(uint4*)&tile[tr][tc + 8] = *(const uint4*)&o[8];
  __syncthreads();
  u16 tmp[16];
#pragma unroll
  for (int u = 0; u < 16; ++u) tmp[u] = tile[tc + u][tr];
  u16* d = dst + (size_t)(n0 + tr) * DIN + i0 + tc;
  *(uint4*)d       = *(const uint4*)&tmp[0];
  *(uint4*)(d + 8) = *(const uint4*)&tmp[8];
}

// ---------------- proj GEMM (2-phase dbuf): qkv projection ----------------
__global__ __launch_bounds__(512, 4) void gemm_proj(
    const u16* __restrict__ A, const u16* __restrict__ BT,
    u16* __restrict__ C0, u16* __restrict__ C1,
    const float* __restrict__ bias)
{
  const int NJ = 2, CH = 4, gx = 64;
  __shared__ u16 As[2][128][64];
  __shared__ u16 Bs[2][NJ * 64][64];
  const int tid = threadIdx.x;
  const int l   = tid & 63;
  const int wid = tid >> 6;
  const int wm  = wid >> 2;
  const int wn  = wid & 3;

  const int nwg = gridDim.x;
  const int cpx = nwg >> 3;
  const int bid = blockIdx.x;
  const int wg  = (bid & 7) * cpx + (bid >> 3);
  const int by  = wg / gx;
  const int bx  = wg - by * gx;
  const int m0  = bx * 128;
  const int n0  = by * (NJ * 64);

  f32x4 acc[4][NJ] = {};
  const int lr = l >> 3;
  const int lc = ((l & 7) ^ lr) * 8;
  const int ca = wid * CH;

  auto STAGE = [&](int buf, int k0) {
#pragma unroll
    for (int i = 0; i < CH; ++i) {
      int c = ca + i;
      if (c < 16) {
        GLOAD_LDS(A + (size_t)(m0 + c * 8 + lr) * DIN + k0 + lc, &As[buf][c * 8][0]);
      } else {
        int cb = c - 16;
        GLOAD_LDS(BT + (size_t)(n0 + cb * 8 + lr) * DIN + k0 + lc, &Bs[buf][cb * 8][0]);
      }
    }
  };

  STAGE(0, 0);
  __syncthreads();
  int cur = 0;
  for (int k0 = 0; k0 < DIN; k0 += 64) {
    if (k0 + 64 < DIN) STAGE(cur ^ 1, k0 + 64);
#pragma unroll
    for (int ks = 0; ks < 2; ++ks) {
      short8 af[4], bg[NJ];
#pragma unroll
      for (int i = 0; i < 4; ++i) {
        int row  = wm * 64 + i * 16 + (l & 15);
        int slot = (ks * 4 + (l >> 4)) ^ (row & 7);
        af[i] = *(const short8*)&As[cur][row][slot * 8];
      }
#pragma unroll
      for (int j = 0; j < NJ; ++j) {
        int row  = wn * (NJ * 16) + j * 16 + (l & 15);
        int slot = (ks * 4 + (l >> 4)) ^ (row & 7);
        bg[j] = *(const short8*)&Bs[cur][row][slot * 8];
      }
#pragma unroll
      for (int i = 0; i < 4; ++i)
#pragma unroll
        for (int j = 0; j < NJ; ++j)
          acc[i][j] = __builtin_amdgcn_mfma_f32_16x16x32_bf16(af[i], bg[j], acc[i][j], 0, 0, 0);
    }
    __syncthreads();
    cur ^= 1;
  }

  const int rbase = (l >> 4) * 4;
  const int cl    = l & 15;
#pragma unroll
  for (int i = 0; i < 4; ++i) {
#pragma unroll
    for (int j = 0; j < NJ; ++j) {
      int col = n0 + wn * (NJ * 16) + j * 16 + cl;
      int row0 = m0 + wm * 64 + i * 16 + rbase;
      float bv_ = bias[col];
      if (n0 < 256) {
#pragma unroll
        for (int q = 0; q < 4; ++q)
          C0[(size_t)(row0 + q) * 256 + col] = f2bf(acc[i][j][q] + bv_);
      } else {
        int b = row0 >> 11, t = row0 & 2047;
        u16 o[4];
#pragma unroll
        for (int q = 0; q < 4; ++q) o[q] = f2bf(acc[i][j][q] + bv_);
        *(uint2*)&C1[((size_t)b * DV + (col - 256)) * SEQ + t] = *(const uint2*)o;
      }
    }
  }
}

// ---------------- Fused attention: P=exp(qk^T) kept on-chip; out = P@V^T / rowsum ----------------
// Block: 128 q-rows x 192 dv-cols, 8 waves, 32 KV-tiles of 64.
// Q hoisted to regs. Per tile: swapped QK^T (mfma(K,Q) -> lane holds 4 consecutive t
// at fixed q) -> exp -> packed b64 swizzled write to Sb -> barrier -> PV from Sb/Vb.
// 3-slot K/V ring, depth-2 prefetch, counted vmcnt(5). Rowsum via ones-MFMA.
__global__ __launch_bounds__(512, 2) void fused_attn(
    const u16* __restrict__ qk, const u16* __restrict__ vT,
    float* __restrict__ out)
{
  const int NT = SEQ / 64;             // 32
  __shared__ u16 Kb[3][64][128];       // 48 KB (k-tiles; slot2 doubles as Q-half0 at start)
  __shared__ u16 Vb[3][192][64];       // 72 KB (v-tiles; slot2 head doubles as Q-half1)
  __shared__ u16 Sb[128][64];          // 16 KB exp(S) tile
  const int tid = threadIdx.x;
  const int l   = tid & 63;
  const int wid = tid >> 6;
  const int tf  = wid >> 1;            // QKT: t-frag group 0..3
  const int qh  = wid & 1;             // QKT: q half
  const int wm  = wid >> 2;            // PV: q half
  const int wn  = wid & 3;             // PV: dv quarter (48 cols)

  const int nwg = gridDim.x;           // 256
  const int cpx = nwg >> 3;
  const int bid = blockIdx.x;
  const int wg  = (bid & 7) * cpx + (bid >> 3);
  const int z   = wg >> 6;
  const int rem = wg & 63;
  const int by  = rem >> 4;
  const int bx  = rem & 15;
  const int m0  = bx * 128;            // q rows
  const int nv0 = by * 192;            // dv cols

  const u16* qkz = qk + (size_t)z * SEQ * 256;
  const u16* vTz = vT + (size_t)z * DV * SEQ;

  // ---- Q -> registers (two 16KB halves via slot-2 LDS regions) ----
  short8 qreg[4][4];                   // [jq][kb]
  {
#pragma unroll
    for (int h = 0; h < 2; ++h) {
      u16* region = (h == 0) ? &Kb[2][0][0] : &Vb[2][0][0];
#pragma unroll
      for (int i = 0; i < 2; ++i) {
        int lrow = i * 32 + wid * 4 + (l >> 4);
        int gs   = (l & 15) ^ (lrow & 7);
        GLOAD_LDS(qkz + (size_t)(m0 + h * 64 + lrow) * 256 + gs * 8,
                  region + (size_t)(i * 32 + wid * 4) * 128);
      }
    }
    wait_vmcnt<0>();
    __builtin_amdgcn_s_barrier();
    const u16* region = (qh == 0) ? &Kb[2][0][0] : &Vb[2][0][0];
#pragma unroll
    for (int jq = 0; jq < 4; ++jq) {
      int lrow = jq * 16 + (l & 15);
#pragma unroll
      for (int kb = 0; kb < 4; ++kb) {
        int slot = (kb * 4 + (l >> 4)) ^ (lrow & 7);
        qreg[jq][kb] = *(const short8*)(region + (size_t)lrow * 128 + slot * 8);
      }
    }
    asm volatile("s_waitcnt lgkmcnt(0)" ::: "memory");
    __builtin_amdgcn_s_barrier();
  }

  f32x4 acc[4][3] = {};
  f32x4 accO[4] = {};
  const short8 kOnes = {16256,16256,16256,16256,16256,16256,16256,16256};

  auto STAGE = [&](int buf, int t0) {
#pragma unroll
    for (int i = 0; i < 2; ++i) {      // K: 16 chunks of 4 rows x 256B
      int c   = wid * 2 + i;
      int row = c * 4 + (l >> 4);
      int gs  = (l & 15) ^ (row & 7);
      GLOAD_LDS(qkz + (size_t)(t0 + row) * 256 + 128 + gs * 8, &Kb[buf][c * 4][0]);
    }
#pragma unroll
    for (int i = 0; i < 3; ++i) {      // V: 24 chunks of 8 rows x 128B
      int c   = wid * 3 + i;
      int row = c * 8 + (l >> 3);
      int gs  = (l & 7) ^ (row & 7);
      GLOAD_LDS(vTz + (size_t)(nv0 + row) * SEQ + t0 + gs * 8, &Vb[buf][c * 8][0]);
    }
  };

  STAGE(0, 0);
  STAGE(1, 64);
  int cur = 0;
  for (int t = 0; t < NT; ++t) {
    if (t == NT - 1) wait_vmcnt<0>(); else wait_vmcnt<5>();
    __builtin_amdgcn_s_barrier();

    // --- swapped QK^T: S^T frag = mfma(K, Q) ---
    f32x4 sacc[4] = {};
    const int klrow = tf * 16 + (l & 15);
#pragma unroll
    for (int kb = 0; kb < 4; ++kb) {
      int slot = (kb * 4 + (l >> 4)) ^ (klrow & 7);
      short8 kf = *(const short8*)&Kb[cur][klrow][slot * 8];
#pragma unroll
      for (int jq = 0; jq < 4; ++jq)
        sacc[jq] = __builtin_amdgcn_mfma_f32_16x16x32_bf16(kf, qreg[jq][kb], sacc[jq], 0, 0, 0);
    }

    const int nxt2 = (cur + 2 >= 3) ? cur - 1 : cur + 2;
    if (t + 2 < NT) STAGE(nxt2, (t + 2) * 64);

    // --- exp + pack b64 -> Sb[q][t] (swizzled; lane has 4 consecutive t at fixed q) ---
#pragma unroll
    for (int jq = 0; jq < 4; ++jq) {
      int q  = qh * 64 + jq * 16 + (l & 15);
      u16 h4[4];
#pragma unroll
      for (int r = 0; r < 4; ++r) h4[r] = f2bf(__expf(sacc[jq][r]));
      int slot16 = tf * 2 + ((l >> 4) >> 1);
      int sw     = slot16 ^ (q & 7);
      *(uint2*)(&Sb[0][0] + (size_t)q * 64 + sw * 8 + ((l >> 4) & 1) * 4) = *(const uint2*)h4;
    }
    asm volatile("s_waitcnt lgkmcnt(0)" ::: "memory");
    __builtin_amdgcn_s_barrier();

    // --- PV: acc += Sb @ Vb^T ; accO += Sb @ ones ---
#pragma unroll
    for (int ks = 0; ks < 2; ++ks) {
      short8 af[4], bg[3];
#pragma unroll
      for (int i = 0; i < 4; ++i) {
        int q    = wm * 64 + i * 16 + (l & 15);
        int slot = (ks * 4 + (l >> 4)) ^ (q & 7);
        af[i] = *(const short8*)(&Sb[0][0] + (size_t)q * 64 + slot * 8);
      }
#pragma unroll
      for (int j = 0; j < 3; ++j) {
        int row  = wn * 48 + j * 16 + (l & 15);
        int slot = (ks * 4 + (l >> 4)) ^ (row & 7);
        bg[j] = *(const short8*)&Vb[cur][row][slot * 8];
      }
      __builtin_amdgcn_s_setprio(1);
#pragma unroll
      for (int i = 0; i < 4; ++i) {
#pragma unroll
        for (int j = 0; j < 3; ++j)
          acc[i][j] = __builtin_amdgcn_mfma_f32_16x16x32_bf16(af[i], bg[j], acc[i][j], 0, 0, 0);
        accO[i] = __builtin_amdgcn_mfma_f32_16x16x32_bf16(af[i], kOnes, accO[i], 0, 0, 0);
      }
      __builtin_amdgcn_s_setprio(0);
    }
    cur = (cur + 1 == 3) ? 0 : cur + 1;
  }

  const int rbase = (l >> 4) * 4;
  const int cl    = l & 15;
#pragma unroll
  for (int i = 0; i < 4; ++i) {
    int row0 = m0 + wm * 64 + i * 16 + rbase;
    f32x4 rs;
#pragma unroll
    for (int q = 0; q < 4; ++q) rs[q] = 1.0f / accO[i][q];
#pragma unroll
    for (int j = 0; j < 3; ++j) {
      int col = nv0 + wn * 48 + j * 16 + cl;
#pragma unroll
      for (int q = 0; q < 4; ++q)
        out[(size_t)z * SEQ * DV + (size_t)(row0 + q) * DV + col] = acc[i][j][q] * rs[q];
    }
  }
}

extern "C" void kernel_launch(void* const* d_in, const int* in_sizes, int n_in,
                              void* d_out, int out_size, void* d_ws, size_t ws_size,
                              hipStream_t stream) {
  const float* x  = (const float*)d_in[0];
  const float* Wq = (const float*)d_in[1];
  const float* bq = (const float*)d_in[2];
  const float* Wk = (const float*)d_in[3];
  const float* bk = (const float*)d_in[4];
  const float* Wv = (const float*)d_in[5];
  const float* bv = (const float*)d_in[6];
  float* out = (float*)d_out;

  size_t off = 0;
  auto alloc = [&](size_t bytes) -> void* {
    void* p = (char*)d_ws + off;
    off += (bytes + 255) & ~(size_t)255;
    return p;
  };
  u16*   xb    = (u16*)alloc((size_t)MTOT * DIN * 2);
  u16*   WbT   = (u16*)alloc((size_t)NQKV * DIN * 2);
  float* biasP = (float*)alloc(NQKV * 4);
  u16*   qk    = (u16*)alloc((size_t)MTOT * 256 * 2);
  u16*   vT    = (u16*)alloc((size_t)BATCH * DV * SEQ * 2);
  if (off > ws_size) return;

  prep<<<dim3(6144 + 192), dim3(256), 0, stream>>>(x, xb, Wq, bq, Wk, bk, Wv, bv, WbT, biasP);

  // proj: [8192,1024] = xb @ WbT^T + bias; writes qk (n<256) and vT (transposed)
  gemm_proj<<<dim3(64 * 8), dim3(512), 0, stream>>>(xb, WbT, qk, vT, biasP);

  // fused attention: 16 q-tiles x 4 dv-chunks x 4 batches
  fused_attn<<<dim3(16 * 4 * BATCH), dim3(512), 0, stream>>>(qk, vT, out);
}